// Round 4
// baseline (170.821 us; speedup 1.0000x reference)
//
#include <hip/hip_runtime.h>
#include <math.h>

#define EPS 1e-6f
#define LN_EPS 1e-5f

static constexpr int Bn = 2, Tn = 2048, Dn = 512, Hn = 8, KT = 2, DH = 64, NC = Tn / 64;
static constexpr int QS = 1536;   // fused qkv bf16 row stride (cols: q|k|v)
static constexpr int NW = 1664;   // padded GEMM width: qkv 1536 | gate 16 | alpha 8 | pad 104

typedef __bf16 bfrag8 __attribute__((ext_vector_type(8)));
typedef float ffrag4 __attribute__((ext_vector_type(4)));
typedef unsigned short us8v __attribute__((ext_vector_type(8)));

__device__ __forceinline__ float wred_sum(float v) {
#pragma unroll
  for (int o = 32; o > 0; o >>= 1) v += __shfl_xor(v, o, 64);
  return v;
}
__device__ __forceinline__ float wred_max(float v) {
#pragma unroll
  for (int o = 32; o > 0; o >>= 1) v = fmaxf(v, __shfl_xor(v, o, 64));
  return v;
}
__device__ __forceinline__ float sigmoidf_(float v) { return 1.0f / (1.0f + expf(-v)); }
__device__ __forceinline__ unsigned short f2bf(float f) {
  unsigned u = __builtin_bit_cast(unsigned, f);
  return (unsigned short)((u + 0x7FFFu + ((u >> 16) & 1u)) >> 16);
}
__device__ __forceinline__ float bf2f(unsigned short u) {
  unsigned v = ((unsigned)u) << 16;
  return __builtin_bit_cast(float, v);
}
// async global->LDS, 16B per lane; LDS dest must be wave-uniform base (+lane*16 by HW)
__device__ __forceinline__ void gload_lds16(const unsigned short* g, unsigned short* l) {
  __builtin_amdgcn_global_load_lds((const __attribute__((address_space(1))) unsigned int*)g,
                                   (__attribute__((address_space(3))) unsigned int*)l, 16, 0, 0);
}

// ---------------------------------------------------------------------------
// QKV GEMM: 512 threads, 128x128 tile, BK=32, 2-barrier K-loop.
// Both operands are fp32 in global and converted bf16 during reg-staging:
//   A-path: x (row fixed per staging thread, k walks)
//   B-path: [Wq;Wk;Wv;Wg;Wa;zero-pad] -- source pointer resolved ONCE before
//           the loop (row is loop-invariant), so no conv kernel / Wc buffer.
// Epilogue: bf16 qkv (col<1536), sigmoid gate (1536..1551), alpha (1552..1559).
// ---------------------------------------------------------------------------
__global__ __launch_bounds__(512) void gemm_qkv(const float* __restrict__ X,
                                                const float* __restrict__ Wq,
                                                const float* __restrict__ Wk,
                                                const float* __restrict__ Wv,
                                                const float* __restrict__ Wg,
                                                const float* __restrict__ Wa,
                                                const float* __restrict__ bg,
                                                const float* __restrict__ ba,
                                                unsigned short* __restrict__ qkvb,
                                                float* __restrict__ gate,
                                                float* __restrict__ alpha) {
  __shared__ unsigned short As[4096];
  __shared__ unsigned short Bs[4096];
  const int tid = threadIdx.x;
  const int lane = tid & 63, wave = tid >> 6;
  const int m0 = blockIdx.y * 128, n0 = blockIdx.x * 128;
  const int mw = (wave >> 1) * 2, nw = (wave & 1) * 4;

  ffrag4 acc[2][4];
#pragma unroll
  for (int i = 0; i < 2; ++i)
#pragma unroll
    for (int j = 0; j < 4; ++j) acc[i][j] = (ffrag4){0.f, 0.f, 0.f, 0.f};

  const int koff = ((tid >> 4) & 3) * 8;
  const float* xg = X + (size_t)(m0 + wave * 16 + (tid & 15)) * Dn + koff;
  const int wrow = n0 + wave * 16 + (tid & 15);
  const float* wsrc;  // loop-invariant: resolved once
  if (wrow < 512)       wsrc = Wq + (size_t)wrow * Dn + koff;
  else if (wrow < 1024) wsrc = Wk + (size_t)(wrow - 512) * Dn + koff;
  else if (wrow < 1536) wsrc = Wv + (size_t)(wrow - 1024) * Dn + koff;
  else if (wrow < 1552) wsrc = Wg + (size_t)(wrow - 1536) * Dn + koff;
  else if (wrow < 1560) wsrc = Wa + (size_t)(wrow - 1552) * Dn + koff;
  else                  wsrc = nullptr;  // pad rows stay zero

  float4 xa0 = *(const float4*)xg;
  float4 xa1 = *(const float4*)(xg + 4);
  float4 wa0 = {0.f, 0.f, 0.f, 0.f}, wa1 = {0.f, 0.f, 0.f, 0.f};
  if (wsrc) { wa0 = *(const float4*)wsrc; wa1 = *(const float4*)(wsrc + 4); }

  for (int k0 = 0; k0 < Dn; k0 += 32) {
    __syncthreads();                 // previous compute done before overwrite
    us8v av, wv;
    av[0] = f2bf(xa0.x); av[1] = f2bf(xa0.y); av[2] = f2bf(xa0.z); av[3] = f2bf(xa0.w);
    av[4] = f2bf(xa1.x); av[5] = f2bf(xa1.y); av[6] = f2bf(xa1.z); av[7] = f2bf(xa1.w);
    wv[0] = f2bf(wa0.x); wv[1] = f2bf(wa0.y); wv[2] = f2bf(wa0.z); wv[3] = f2bf(wa0.w);
    wv[4] = f2bf(wa1.x); wv[5] = f2bf(wa1.y); wv[6] = f2bf(wa1.z); wv[7] = f2bf(wa1.w);
    *(us8v*)&As[tid * 8] = av;
    *(us8v*)&Bs[tid * 8] = wv;
    if (k0 + 32 < Dn) {              // depth-1 reg prefetch (fp32), hidden under MFMAs
      xa0 = *(const float4*)(xg + k0 + 32);
      xa1 = *(const float4*)(xg + k0 + 36);
      if (wsrc) {
        wa0 = *(const float4*)(wsrc + k0 + 32);
        wa1 = *(const float4*)(wsrc + k0 + 36);
      }
    }
    __syncthreads();                 // tile visible
    bfrag8 af[2], bf_[4];
#pragma unroll
    for (int mt = 0; mt < 2; ++mt)
      af[mt] = __builtin_bit_cast(bfrag8, *(const uint4*)&As[((mw + mt) * 64 + lane) * 8]);
#pragma unroll
    for (int nt = 0; nt < 4; ++nt)
      bf_[nt] = __builtin_bit_cast(bfrag8, *(const uint4*)&Bs[((nw + nt) * 64 + lane) * 8]);
#pragma unroll
    for (int mt = 0; mt < 2; ++mt)
#pragma unroll
      for (int nt = 0; nt < 4; ++nt)
        acc[mt][nt] = __builtin_amdgcn_mfma_f32_16x16x32_bf16(af[mt], bf_[nt], acc[mt][nt], 0, 0, 0);
  }

  const int quad = lane >> 4, l15 = lane & 15;
#pragma unroll
  for (int nt = 0; nt < 4; ++nt) {
    int col = n0 + (nw + nt) * 16 + l15;
#pragma unroll
    for (int mt = 0; mt < 2; ++mt) {
#pragma unroll
      for (int r = 0; r < 4; ++r) {
        int row = m0 + (mw + mt) * 16 + quad * 4 + r;
        float val = acc[mt][nt][r];
        if (col < 1536) {
          qkvb[(size_t)row * QS + col] = f2bf(val);
        } else if (col < 1552) {
          gate[(size_t)row * (Hn * KT) + (col - 1536)] = sigmoidf_(val + bg[col - 1536]);
        } else if (col < 1560) {
          alpha[(size_t)row * Hn + (col - 1552)] = sigmoidf_(val + ba[col - 1552]);
        }
      }
    }
  }
}

// ---------------------------------------------------------------------------
// Out-proj GEMM: 256 threads, 64x64 tile, BK=32 (round-2 proven structure).
// A (ypre bf16) via async global_load_lds; W from fp32 Wo, converted in the
// reg-stager (row loop-invariant) -- no conv kernel / Wob buffer.
// ---------------------------------------------------------------------------
__global__ __launch_bounds__(256) void gemm_out(const unsigned short* __restrict__ A,
                                                const float* __restrict__ Wo,
                                                const float* __restrict__ bias,
                                                float* __restrict__ C) {
  __shared__ unsigned short As[2048];
  __shared__ unsigned short Bs[2048];
  const int tid = threadIdx.x;
  const int lane = tid & 63, wave = tid >> 6;
  const int m0 = blockIdx.y * 64, n0 = blockIdx.x * 64;
  const int mw = (wave >> 1) * 2, nw = (wave & 1) * 2;

  ffrag4 acc[2][2];
#pragma unroll
  for (int i = 0; i < 2; ++i)
#pragma unroll
    for (int j = 0; j < 2; ++j) acc[i][j] = (ffrag4){0.f, 0.f, 0.f, 0.f};

  const int koff = ((tid >> 4) & 3) * 8;
  const unsigned short* ag = A + (size_t)(m0 + wave * 16 + (tid & 15)) * Dn + koff;
  const float* wg = Wo + (size_t)(n0 + wave * 16 + (tid & 15)) * Dn + koff;
  unsigned short* asl = &As[wave * 512];  // wave-uniform LDS base (+lane*16B by HW)

  float4 wa0 = *(const float4*)wg;
  float4 wa1 = *(const float4*)(wg + 4);

  for (int k0 = 0; k0 < Dn; k0 += 32) {
    __syncthreads();
    us8v wv;
    wv[0] = f2bf(wa0.x); wv[1] = f2bf(wa0.y); wv[2] = f2bf(wa0.z); wv[3] = f2bf(wa0.w);
    wv[4] = f2bf(wa1.x); wv[5] = f2bf(wa1.y); wv[6] = f2bf(wa1.z); wv[7] = f2bf(wa1.w);
    *(us8v*)&Bs[tid * 8] = wv;
    gload_lds16(ag + k0, asl);
    if (k0 + 32 < Dn) {
      wa0 = *(const float4*)(wg + k0 + 32);
      wa1 = *(const float4*)(wg + k0 + 36);
    }
    __syncthreads();
    bfrag8 af[2], bf_[2];
#pragma unroll
    for (int mt = 0; mt < 2; ++mt)
      af[mt] = __builtin_bit_cast(bfrag8, *(const uint4*)&As[((mw + mt) * 64 + lane) * 8]);
#pragma unroll
    for (int nt = 0; nt < 2; ++nt)
      bf_[nt] = __builtin_bit_cast(bfrag8, *(const uint4*)&Bs[((nw + nt) * 64 + lane) * 8]);
#pragma unroll
    for (int mt = 0; mt < 2; ++mt)
#pragma unroll
      for (int nt = 0; nt < 2; ++nt)
        acc[mt][nt] = __builtin_amdgcn_mfma_f32_16x16x32_bf16(af[mt], bf_[nt], acc[mt][nt], 0, 0, 0);
  }

  const int quad = lane >> 4, l15 = lane & 15;
#pragma unroll
  for (int nt = 0; nt < 2; ++nt) {
    int col = n0 + (nw + nt) * 16 + l15;
    float bb = bias[col];
#pragma unroll
    for (int mt = 0; mt < 2; ++mt) {
#pragma unroll
      for (int r = 0; r < 4; ++r) {
        int row = m0 + (mw + mt) * 16 + quad * 4 + r;
        C[(size_t)row * Dn + col] = acc[mt][nt][r] + bb;
      }
    }
  }
}

// ---------------------------------------------------------------------------
// Block per (b,h,c): S^T_k = (w_k o V)^T @ K via MFMA (fp32 S^T out), z_k via
// wred, sval exported. LDS-transposes K,V; exports V^T tiles to vT.
// ---------------------------------------------------------------------------
__global__ __launch_bounds__(256) void chunk_sums(const unsigned short* __restrict__ qkvb,
                                                  const float* __restrict__ gate,
                                                  const float* __restrict__ decay,
                                                  float* __restrict__ S,
                                                  float* __restrict__ Zc,
                                                  float* __restrict__ svalb,
                                                  unsigned short* __restrict__ vT) {
  __shared__ unsigned short sK[64 * 72];
  __shared__ unsigned short sV[64 * 72];
  __shared__ unsigned short sKT[64 * 72];   // K^T: [i][t], stride 72
  __shared__ unsigned short sVT[64 * 72];   // V^T: [j][t], stride 72
  __shared__ float red4[256];
  __shared__ float sval_s[64];
  __shared__ float gk[KT][64];
  __shared__ float pwr[KT][64];
  __shared__ float wcomb[KT][64];
  const int c = blockIdx.x, h = blockIdx.y, b = blockIdx.z;
  const int c0 = c * 64;
  const int tid = threadIdx.x, wave = tid >> 6, lane = tid & 63;
  const int quad = lane >> 4, l15 = lane & 15;

  {
    int row = tid >> 2, cg = tid & 3;
    const us8v* ksrc = (const us8v*)&qkvb[(size_t)(b * Tn + c0 + row) * QS + 512 + h * DH + cg * 16];
    *(us8v*)&sK[row * 72 + cg * 16] = ksrc[0];
    *(us8v*)&sK[row * 72 + cg * 16 + 8] = ksrc[1];
    const us8v* vsrc = (const us8v*)&qkvb[(size_t)(b * Tn + c0 + row) * QS + 1024 + h * DH + cg * 16];
    *(us8v*)&sV[row * 72 + cg * 16] = vsrc[0];
    *(us8v*)&sV[row * 72 + cg * 16 + 8] = vsrc[1];
  }
  if (tid < 128) {
    int s = tid >> 1, k2 = tid & 1;
    gk[k2][s] = gate[((size_t)(b * Tn + c0 + s) * Hn + h) * KT + k2];
  } else {
    int t2 = tid - 128;
    int k2 = t2 >> 6, d = t2 & 63;
    pwr[k2][d] = powf(sigmoidf_(decay[h * KT + k2]), (float)d);
  }
  __syncthreads();
  {
    int row = tid >> 2, cg = tid & 3;
    float acc = 0.f;
#pragma unroll
    for (int u = 0; u < 16; ++u) acc += fabsf(bf2f(sK[row * 72 + cg * 16 + u]));
    red4[tid] = acc;
  }
  if (tid >= 128) {
    int t2 = tid - 128;
    int k2 = t2 >> 6, d = t2 & 63;
    wcomb[k2][d] = gk[k2][d] * pwr[k2][63 - d];
  }
  __syncthreads();
  if (tid < 64) {
    float sv = (red4[tid * 4] + red4[tid * 4 + 1] + red4[tid * 4 + 2] + red4[tid * 4 + 3]) *
                   (1.f / 64.f) + EPS;
    sval_s[tid] = sv;
    svalb[((size_t)(b * Hn + h)) * Tn + c0 + tid] = sv;
  }
  // LDS transpose of K and V; V^T also exported to vT (global).
  {
    int j = tid >> 2, tg = tid & 3;
    us8v a0, a1, b0, b1;
#pragma unroll
    for (int u = 0; u < 8; ++u) {
      a0[u] = sV[(tg * 16 + u) * 72 + j];
      a1[u] = sV[(tg * 16 + 8 + u) * 72 + j];
      b0[u] = sK[(tg * 16 + u) * 72 + j];
      b1[u] = sK[(tg * 16 + 8 + u) * 72 + j];
    }
    *(us8v*)&sVT[j * 72 + tg * 16] = a0;
    *(us8v*)&sVT[j * 72 + tg * 16 + 8] = a1;
    *(us8v*)&sKT[j * 72 + tg * 16] = b0;
    *(us8v*)&sKT[j * 72 + tg * 16 + 8] = b1;
    size_t vrow = ((size_t)((b * Hn + h) * 64 + j)) * Tn + c0 + tg * 16;
    *(us8v*)&vT[vrow] = a0;
    *(us8v*)&vT[vrow + 8] = a1;
  }
  __syncthreads();
  if (wave < 2) {
    const int kx = wave;
    float v = wcomb[kx][lane] * sval_s[lane];
    v = wred_sum(v);
    if (lane == 0) Zc[((size_t)((b * Hn + h) * KT + kx)) * NC + c] = v;
  }

  // S^T = (w o V)^T @ K : A-frag rows m=j (V dh), B-frag cols n=i (K dh).
  us8v kf2[4][2];
#pragma unroll
  for (int nt = 0; nt < 4; ++nt)
#pragma unroll
    for (int ks = 0; ks < 2; ++ks)
      kf2[nt][ks] = *(const us8v*)&sKT[(nt * 16 + l15) * 72 + ks * 32 + quad * 8];

  const int jrow = wave * 16 + l15;
  us8v vraw[2];
  vraw[0] = *(const us8v*)&sVT[jrow * 72 + quad * 8];
  vraw[1] = *(const us8v*)&sVT[jrow * 72 + 32 + quad * 8];

#pragma unroll
  for (int k = 0; k < KT; ++k) {
    us8v af[2];
#pragma unroll
    for (int ks = 0; ks < 2; ++ks) {
      float4 w0 = *(const float4*)&wcomb[k][ks * 32 + quad * 8];
      float4 w1 = *(const float4*)&wcomb[k][ks * 32 + quad * 8 + 4];
      af[ks][0] = f2bf(w0.x * bf2f(vraw[ks][0]));
      af[ks][1] = f2bf(w0.y * bf2f(vraw[ks][1]));
      af[ks][2] = f2bf(w0.z * bf2f(vraw[ks][2]));
      af[ks][3] = f2bf(w0.w * bf2f(vraw[ks][3]));
      af[ks][4] = f2bf(w1.x * bf2f(vraw[ks][4]));
      af[ks][5] = f2bf(w1.y * bf2f(vraw[ks][5]));
      af[ks][6] = f2bf(w1.z * bf2f(vraw[ks][6]));
      af[ks][7] = f2bf(w1.w * bf2f(vraw[ks][7]));
    }
    ffrag4 acc[4];
#pragma unroll
    for (int nt = 0; nt < 4; ++nt) acc[nt] = (ffrag4){0.f, 0.f, 0.f, 0.f};
#pragma unroll
    for (int nt = 0; nt < 4; ++nt)
#pragma unroll
      for (int ks = 0; ks < 2; ++ks)
        acc[nt] = __builtin_amdgcn_mfma_f32_16x16x32_bf16(
            __builtin_bit_cast(bfrag8, af[ks]), __builtin_bit_cast(bfrag8, kf2[nt][ks]), acc[nt], 0, 0, 0);
    const size_t sb = ((size_t)((b * Hn + h) * KT + k) * NC + c) * 4096;
#pragma unroll
    for (int nt = 0; nt < 4; ++nt)
#pragma unroll
      for (int r = 0; r < 4; ++r)
        S[sb + (size_t)(wave * 16 + quad * 4 + r) * 64 + nt * 16 + l15] = acc[nt][r];
  }
}

// ---------------------------------------------------------------------------
// Serial scan: fp32 S^T in, fp32 accumulator, bf16 Hinit^T out (elementwise,
// layout-agnostic). Batch-4 loads: 4 independent loads in flight per step.
// ---------------------------------------------------------------------------
__global__ __launch_bounds__(256) void scan_chunks(const float* __restrict__ S,
                                                   const float* __restrict__ Zc,
                                                   const float* __restrict__ decay,
                                                   unsigned short* __restrict__ Hinit,
                                                   float* __restrict__ Zinit) {
  const int bhk = blockIdx.x, slice = blockIdx.y;
  const int k = bhk % KT, h = (bhk / KT) % Hn;
  const float lam = sigmoidf_(decay[h * KT + k]);
  const float lam64 = powf(lam, 64.f);
  const int tid = threadIdx.x;
  const size_t base = (size_t)bhk * NC * 4096 + (size_t)slice * 512 + (size_t)tid * 2;
  float2 st = {0.f, 0.f};
  float2 sv[4];
#pragma unroll
  for (int j = 0; j < 4; ++j) sv[j] = *(const float2*)&S[base + (size_t)j * 4096];
  for (int cb = 0; cb < NC; cb += 4) {
    float2 nx[4] = {sv[0], sv[1], sv[2], sv[3]};
    if (cb + 4 < NC) {
#pragma unroll
      for (int j = 0; j < 4; ++j) nx[j] = *(const float2*)&S[base + (size_t)(cb + 4 + j) * 4096];
    }
#pragma unroll
    for (int j = 0; j < 4; ++j) {
      size_t off = base + (size_t)(cb + j) * 4096;
      ushort2 o;
      o.x = f2bf(st.x); o.y = f2bf(st.y);
      *(ushort2*)&Hinit[off] = o;
      st.x = lam64 * st.x + sv[j].x;
      st.y = lam64 * st.y + sv[j].y;
    }
#pragma unroll
    for (int j = 0; j < 4; ++j) sv[j] = nx[j];
  }
  if (slice == 0 && tid < 64) {
    float v = (tid < NC) ? Zc[bhk * NC + tid] : 0.f;
    float lp = lam64;
#pragma unroll
    for (int o = 1; o < 32; o <<= 1) {
      float t2 = __shfl_up(v, o, 64);
      if (tid >= o) v += lp * t2;
      lp *= lp;
    }
    float prev = __shfl_up(v, 1, 64);
    if (tid < NC) Zinit[bhk * NC + tid] = (tid == 0) ? 0.f : prev;
  }
}

// ---------------------------------------------------------------------------
// Block per (b,h,c): chunked attention. Hinit^T and V^T arrive pre-transposed,
// so every LDS->MFMA B-fragment is a contiguous ds_read_b128. Single staging
// barrier; prev-half V comes straight from sVTa (no restage).
// ---------------------------------------------------------------------------
__global__ __launch_bounds__(256) void attn_chunk(const unsigned short* __restrict__ qkvb,
                                                  const float* __restrict__ gate,
                                                  const float* __restrict__ alpha,
                                                  const float* __restrict__ decay,
                                                  const unsigned short* __restrict__ Hinit,
                                                  const float* __restrict__ Zinit,
                                                  const float* __restrict__ svalb,
                                                  const unsigned short* __restrict__ vT,
                                                  unsigned short* __restrict__ ypre) {
  __shared__ float sS[64][132];               // raw scores -> probs (33.8 KB)
  __shared__ unsigned short sHT[KT][64 * 72]; // Hinit^T staging [j][i] (18.4 KB)
  __shared__ unsigned short sVTa[64 * 136];   // V^T staging [j][t prev|cur] (17.4 KB)
  __shared__ float sval_s[64];
  __shared__ float gk[KT][64];
  __shared__ float sz[KT][64];
  __shared__ float pw[KT][66];
  __shared__ float wt2[KT][64];               // g_s * lam^-s
  __shared__ float zin[KT];

  const int c = blockIdx.x, h = blockIdx.y, b = blockIdx.z;
  const int c0 = c * 64;
  const int tid = threadIdx.x;
  const int wave = tid >> 6, lane = tid & 63;
  const int quad = lane >> 4, l15 = lane & 15;
  const int mt = wave;

  // ---------------- prologue ----------------
  if (tid < 64) sval_s[tid] = svalb[((size_t)(b * Hn + h)) * Tn + c0 + tid];
  if (tid < 128) {
    int s = tid >> 1, k2 = tid & 1;
    gk[k2][s] = gate[((size_t)(b * Tn + c0 + s) * Hn + h) * KT + k2];
  }
  if (tid >= 128) {
    int t2 = tid - 128;
    int k2 = t2 >> 6, d = t2 & 63;
    float lamv = sigmoidf_(decay[h * KT + k2]);
    pw[k2][d] = powf(lamv, (float)d);
  }
  if (tid < 2) {
    float lamv = sigmoidf_(decay[h * KT + tid]);
    pw[tid][64] = powf(lamv, 64.f);
    zin[tid] = Zinit[((size_t)((b * Hn + h) * KT + tid)) * NC + c];
  }
  __syncthreads();
  if (tid >= 128) {
    int t2 = tid - 128;
    int k2 = t2 >> 6, d = t2 & 63;
    wt2[k2][d] = gk[k2][d] / pw[k2][d];   // lam^-d = 1/pw[d] (rcp, not powf)
  }
  if (wave < 2) {
    const int kx = wave;
    float v = gk[kx][lane] * sval_s[lane];
#pragma unroll
    for (int o = 1; o < 64; o <<= 1) {
      float t2 = __shfl_up(v, o, 64);
      if (lane >= o) v += pw[kx][o] * t2;
    }
    sz[kx][lane] = v + pw[kx][lane + 1] * zin[kx];
  }
  // wt2/sz consumed in C2, after the staging barrier below.

  // -------- issue staging loads early (regs): Hinit^T k0,k1 + V^T ----------
  us8v stgH[KT][2], stgV[4];
  {
    int j = tid >> 2, cg = tid & 3;
#pragma unroll
    for (int k = 0; k < KT; ++k) {
      const size_t hb = ((size_t)((b * Hn + h) * KT + k) * NC + c) * 4096;
      stgH[k][0] = *(const us8v*)&Hinit[hb + j * 64 + cg * 16];
      stgH[k][1] = *(const us8v*)&Hinit[hb + j * 64 + cg * 16 + 8];
    }
    const size_t vrow = ((size_t)((b * Hn + h) * 64 + j)) * Tn;
    const us8v z8 = (us8v){0, 0, 0, 0, 0, 0, 0, 0};
#pragma unroll
    for (int q = 0; q < 4; ++q) {
      int tt = c0 - 64 + cg * 32 + q * 8;
      stgV[q] = (tt >= 0) ? *(const us8v*)&vT[vrow + tt] : z8;
    }
  }

  // ---------------- Q fragments ----------------
  us8v qf[2];
  {
    const size_t qrow = (size_t)(b * Tn + c0 + mt * 16 + l15) * QS + h * DH;
    qf[0] = *(const us8v*)&qkvb[qrow + quad * 8];
    qf[1] = *(const us8v*)&qkvb[qrow + 32 + quad * 8];
  }

  // ---------------- phase A: raw scores = Qc @ Kwin^T ----------------------
#pragma unroll
  for (int nt = 0; nt < 8; ++nt) {
    int rowg = c0 - 64 + nt * 16 + l15;
    us8v kf0 = (us8v){0, 0, 0, 0, 0, 0, 0, 0}, kf1 = kf0;
    if (rowg >= 0) {
      const size_t kb_ = (size_t)(b * Tn + rowg) * QS + 512 + h * DH;
      kf0 = *(const us8v*)&qkvb[kb_ + quad * 8];
      kf1 = *(const us8v*)&qkvb[kb_ + 32 + quad * 8];
    }
    ffrag4 a = (ffrag4){0.f, 0.f, 0.f, 0.f};
    a = __builtin_amdgcn_mfma_f32_16x16x32_bf16(__builtin_bit_cast(bfrag8, qf[0]),
                                                __builtin_bit_cast(bfrag8, kf0), a, 0, 0, 0);
    a = __builtin_amdgcn_mfma_f32_16x16x32_bf16(__builtin_bit_cast(bfrag8, qf[1]),
                                                __builtin_bit_cast(bfrag8, kf1), a, 0, 0, 0);
#pragma unroll
    for (int r = 0; r < 4; ++r) sS[mt * 16 + quad * 4 + r][nt * 16 + l15] = a[r];
  }

  // -------- commit staging regs to LDS, single barrier ---------------------
  {
    int j = tid >> 2, cg = tid & 3;
#pragma unroll
    for (int k = 0; k < KT; ++k) {
      *(us8v*)&sHT[k][j * 72 + cg * 16] = stgH[k][0];
      *(us8v*)&sHT[k][j * 72 + cg * 16 + 8] = stgH[k][1];
    }
#pragma unroll
    for (int q = 0; q < 4; ++q)
      *(us8v*)&sVTa[j * 136 + cg * 32 + q * 8] = stgV[q];
  }
  __syncthreads();

  // ---------------- phase C1: accH_k = Q @ Hinit_k (contiguous b128) -------
  ffrag4 accH[KT][4];
#pragma unroll
  for (int k = 0; k < KT; ++k)
#pragma unroll
    for (int nt = 0; nt < 4; ++nt) accH[k][nt] = (ffrag4){0.f, 0.f, 0.f, 0.f};
#pragma unroll
  for (int k = 0; k < KT; ++k) {
#pragma unroll
    for (int nt = 0; nt < 4; ++nt) {
#pragma unroll
      for (int ks = 0; ks < 2; ++ks) {
        us8v g = *(const us8v*)&sHT[k][(nt * 16 + l15) * 72 + ks * 32 + quad * 8];
        accH[k][nt] = __builtin_amdgcn_mfma_f32_16x16x32_bf16(
            __builtin_bit_cast(bfrag8, qf[ks]), __builtin_bit_cast(bfrag8, g), accH[k][nt], 0, 0, 0);
      }
    }
  }

  // ---------------- cur-half V^T B-frags (contiguous b128) -----------------
  us8v vf[4][2];
#pragma unroll
  for (int nt = 0; nt < 4; ++nt)
#pragma unroll
    for (int ks = 0; ks < 2; ++ks)
      vf[nt][ks] = *(const us8v*)&sVTa[(nt * 16 + l15) * 136 + 64 + ks * 32 + quad * 8];

  // ---------------- phase C2 + combine into accY ---------------------------
  const int i_loc = mt * 16 + l15;
  ffrag4 accY[4];
#pragma unroll
  for (int nt = 0; nt < 4; ++nt) accY[nt] = (ffrag4){0.f, 0.f, 0.f, 0.f};
#pragma unroll
  for (int k = 0; k < KT; ++k) {
    const float lam_i = pw[k][i_loc];
    us8v af[2];
#pragma unroll
    for (int ks = 0; ks < 2; ++ks) {
      int sb_ = ks * 32 + quad * 8;
      float4 p0 = *(const float4*)&sS[i_loc][64 + sb_];
      float4 p1 = *(const float4*)&sS[i_loc][64 + sb_ + 4];
      float4 w0 = *(const float4*)&wt2[k][sb_];
      float4 w1 = *(const float4*)&wt2[k][sb_ + 4];
      float e[8] = {p0.x * w0.x, p0.y * w0.y, p0.z * w0.z, p0.w * w0.w,
                    p1.x * w1.x, p1.y * w1.y, p1.z * w1.z, p1.w * w1.w};
#pragma unroll
      for (int j = 0; j < 8; ++j) {
        float v = (sb_ + j <= i_loc) ? e[j] * lam_i : 0.f;
        af[ks][j] = f2bf(v);
      }
    }
    ffrag4 aD[4];
#pragma unroll
    for (int nt = 0; nt < 4; ++nt) aD[nt] = (ffrag4){0.f, 0.f, 0.f, 0.f};
#pragma unroll
    for (int nt = 0; nt < 4; ++nt)
#pragma unroll
      for (int ks = 0; ks < 2; ++ks)
        aD[nt] = __builtin_amdgcn_mfma_f32_16x16x32_bf16(
            __builtin_bit_cast(bfrag8, af[ks]), __builtin_bit_cast(bfrag8, vf[nt][ks]), aD[nt], 0, 0, 0);
#pragma unroll
    for (int nt = 0; nt < 4; ++nt) {
#pragma unroll
      for (int r = 0; r < 4; ++r) {
        int il = mt * 16 + quad * 4 + r;
        float invz = 1.f / (sz[k][il] + EPS);
        accY[nt][r] += (pw[k][il + 1] * accH[k][nt][r] + aD[nt][r]) * invz;
      }
    }
  }

  // ---------------- phase D: in-place masked ALiBi softmax -----------------
  {
    const float slope = exp2f(-8.f * (float)(h + 1) / (float)Hn);
    for (int rr = 0; rr < 16; ++rr) {
      const int i = mt * 16 + rr;
      float s0v = sS[i][lane], s1v = sS[i][lane + 64];
      bool va = (lane >= i + 1) && (c0 - 64 + lane >= 0);
      bool vb2 = (lane <= i);
      s0v = va  ? s0v - slope * (float)(i + 64 - lane) : -1e30f;
      s1v = vb2 ? s1v - slope * (float)(i - lane) : -1e30f;
      float m = wred_max(fmaxf(s0v, s1v));
      float p0 = __expf(s0v - m), p1 = __expf(s1v - m);
      float inv = 1.f / wred_sum(p0 + p1);
      sS[i][lane] = p0 * inv;
      sS[i][lane + 64] = p1 * inv;
    }
  }

  // ---------------- phase E: yloc = P @ Vwin (all frags from sVTa) ---------
  ffrag4 accL[4];
#pragma unroll
  for (int nt = 0; nt < 4; ++nt) accL[nt] = (ffrag4){0.f, 0.f, 0.f, 0.f};
  us8v pf[2];
#pragma unroll
  for (int ks = 0; ks < 2; ++ks) {
    int sb_ = ks * 32 + quad * 8;
    float4 p0 = *(const float4*)&sS[i_loc][64 + sb_];
    float4 p1 = *(const float4*)&sS[i_loc][64 + sb_ + 4];
    float e[8] = {p0.x, p0.y, p0.z, p0.w, p1.x, p1.y, p1.z, p1.w};
#pragma unroll
    for (int j = 0; j < 8; ++j) pf[ks][j] = f2bf(e[j]);
  }
#pragma unroll
  for (int nt = 0; nt < 4; ++nt)
#pragma unroll
    for (int ks = 0; ks < 2; ++ks)
      accL[nt] = __builtin_amdgcn_mfma_f32_16x16x32_bf16(
          __builtin_bit_cast(bfrag8, pf[ks]), __builtin_bit_cast(bfrag8, vf[nt][ks]), accL[nt], 0, 0, 0);

  // prev-half directly from sVTa (no restage, no barriers)
#pragma unroll
  for (int ks = 0; ks < 2; ++ks) {
    int sb_ = ks * 32 + quad * 8;
    float4 p0 = *(const float4*)&sS[i_loc][sb_];
    float4 p1 = *(const float4*)&sS[i_loc][sb_ + 4];
    float e[8] = {p0.x, p0.y, p0.z, p0.w, p1.x, p1.y, p1.z, p1.w};
#pragma unroll
    for (int j = 0; j < 8; ++j) pf[ks][j] = f2bf(e[j]);
  }
#pragma unroll
  for (int nt = 0; nt < 4; ++nt) {
#pragma unroll
    for (int ks = 0; ks < 2; ++ks) {
      us8v g = *(const us8v*)&sVTa[(nt * 16 + l15) * 136 + ks * 32 + quad * 8];
      accL[nt] = __builtin_amdgcn_mfma_f32_16x16x32_bf16(
          __builtin_bit_cast(bfrag8, pf[ks]), __builtin_bit_cast(bfrag8, g), accL[nt], 0, 0, 0);
    }
  }

  // ---------------- phase F: combine + bf16 write --------------------------
#pragma unroll
  for (int nt = 0; nt < 4; ++nt) {
#pragma unroll
    for (int r = 0; r < 4; ++r) {
      int il = mt * 16 + quad * 4 + r;
      int tt = c0 + il;
      float av = alpha[((size_t)(b * Tn + tt)) * Hn + h];
      float val = av * accL[nt][r] + (1.f - av) * accY[nt][r];
      ypre[(size_t)(b * Tn + tt) * Dn + h * DH + nt * 16 + l15] = f2bf(val);
    }
  }
}

// ---------------------------------------------------------------------------
// out = LayerNorm(x + proj) * gamma + beta
// ---------------------------------------------------------------------------
__global__ __launch_bounds__(256) void ln_kernel(const float* __restrict__ x,
                                                 const float* __restrict__ proj,
                                                 const float* __restrict__ gamma,
                                                 const float* __restrict__ beta,
                                                 float* __restrict__ out) {
  const int row = blockIdx.x;
  const int tid = threadIdx.x;
  const int wave = tid >> 6, lane = tid & 63;
  const size_t base = (size_t)row * Dn;
  __shared__ float red[8];
  float r0 = x[base + tid] + proj[base + tid];
  float r1 = x[base + tid + 256] + proj[base + tid + 256];
  float s = wred_sum(r0 + r1);
  if (lane == 0) red[wave] = s;
  __syncthreads();
  float mu = (red[0] + red[1] + red[2] + red[3]) * (1.f / (float)Dn);
  float d0 = r0 - mu, d1 = r1 - mu;
  float q = wred_sum(d0 * d0 + d1 * d1);
  if (lane == 0) red[4 + wave] = q;
  __syncthreads();
  float var = (red[4] + red[5] + red[6] + red[7]) * (1.f / (float)Dn);
  float inv = rsqrtf(var + LN_EPS);
  out[base + tid]       = d0 * inv * gamma[tid]       + beta[tid];
  out[base + tid + 256] = d1 * inv * gamma[tid + 256] + beta[tid + 256];
}

// ---------------------------------------------------------------------------
extern "C" void kernel_launch(void* const* d_in, const int* in_sizes, int n_in,
                              void* d_out, int out_size, void* d_ws, size_t ws_size,
                              hipStream_t stream) {
  const float* x     = (const float*)d_in[0];
  const float* Wq    = (const float*)d_in[1];
  const float* Wk    = (const float*)d_in[2];
  const float* Wv    = (const float*)d_in[3];
  const float* Wg    = (const float*)d_in[4];
  const float* bg    = (const float*)d_in[5];
  const float* Wa    = (const float*)d_in[6];
  const float* ba    = (const float*)d_in[7];
  const float* Wo    = (const float*)d_in[8];
  const float* bo    = (const float*)d_in[9];
  const float* decay = (const float*)d_in[10];
  const float* gamma = (const float*)d_in[11];
  const float* beta  = (const float*)d_in[12];
  float* out = (float*)d_out;

  const size_t NTOK = (size_t)Bn * Tn;                  // 4096
  const size_t NST  = (size_t)Bn * Hn * KT * NC * 4096; // 4194304 state elems
  float* ws = (float*)d_ws;
  float* proj  = ws; ws += NTOK * Dn;   // fp32 proj; bf16 vT overlays (time-disjoint)
  float* Sb    = ws; ws += NST;    // fp32 S^T
  float* gateb = ws; ws += NTOK * Hn * KT;
  float* alphb = ws; ws += NTOK * Hn;
  float* Zcb   = ws; ws += (size_t)Bn * Hn * KT * NC;
  float* Zib   = ws; ws += (size_t)Bn * Hn * KT * NC;
  float* svalb = ws; ws += (size_t)Bn * Hn * Tn;
  unsigned short* us = (unsigned short*)ws;
  unsigned short* Hib  = us; us += NST;                  // bf16 Hinit^T
  unsigned short* ypre = us; us += NTOK * Dn;
  unsigned short* qkvb = us; us += NTOK * QS;
  // vT (bf16 V^T, [B*H*64][Tn] = 4.2 MB) overlays proj (8.4 MB): vT is dead
  // before gemm_out writes proj (attn finished), so regions are time-disjoint.
  unsigned short* vT = (unsigned short*)proj;

  gemm_qkv<<<dim3(NW / 128, (int)NTOK / 128), 512, 0, stream>>>(
      x, Wq, Wk, Wv, Wg, Wa, bg, ba, qkvb, gateb, alphb);

  chunk_sums<<<dim3(NC, Hn, Bn), 256, 0, stream>>>(qkvb, gateb, decay, Sb, Zcb, svalb, vT);
  scan_chunks<<<dim3(Bn * Hn * KT, 8), 256, 0, stream>>>(Sb, Zcb, decay, Hib, Zib);

  attn_chunk<<<dim3(NC, Hn, Bn), 256, 0, stream>>>(qkvb, gateb, alphb, decay,
                                                   Hib, Zib, svalb, vT, ypre);

  gemm_out<<<dim3(Dn / 64, (int)NTOK / 64), 256, 0, stream>>>(ypre, Wo, bo, proj);
  ln_kernel<<<(int)NTOK, 256, 0, stream>>>(x, proj, gamma, beta, out);
}

// Round 6
// 160.324 us; speedup vs baseline: 1.0655x; 1.0655x over previous
//
#include <hip/hip_runtime.h>
#include <math.h>

#define EPS 1e-6f
#define LN_EPS 1e-5f

static constexpr int Bn = 2, Tn = 2048, Dn = 512, Hn = 8, KT = 2, DH = 64, NC = Tn / 64;
static constexpr int QS = 1536;   // fused qkv bf16 row stride (cols: q|k|v)
static constexpr int NW = 1664;   // padded GEMM width: qkv 1536 | gate 16 | alpha 8 | pad 104

typedef __bf16 bfrag8 __attribute__((ext_vector_type(8)));
typedef float ffrag4 __attribute__((ext_vector_type(4)));
typedef unsigned short us8v __attribute__((ext_vector_type(8)));

__device__ __forceinline__ float wred_sum(float v) {
#pragma unroll
  for (int o = 32; o > 0; o >>= 1) v += __shfl_xor(v, o, 64);
  return v;
}
__device__ __forceinline__ float wred_max(float v) {
#pragma unroll
  for (int o = 32; o > 0; o >>= 1) v = fmaxf(v, __shfl_xor(v, o, 64));
  return v;
}
__device__ __forceinline__ float sigmoidf_(float v) { return 1.0f / (1.0f + expf(-v)); }
__device__ __forceinline__ unsigned short f2bf(float f) {
  unsigned u = __builtin_bit_cast(unsigned, f);
  return (unsigned short)((u + 0x7FFFu + ((u >> 16) & 1u)) >> 16);
}
__device__ __forceinline__ float bf2f(unsigned short u) {
  unsigned v = ((unsigned)u) << 16;
  return __builtin_bit_cast(float, v);
}
// async global->LDS, 16B per lane; LDS dest must be wave-uniform base (+lane*16 by HW)
__device__ __forceinline__ void gload_lds16(const unsigned short* g, unsigned short* l) {
  __builtin_amdgcn_global_load_lds((const __attribute__((address_space(1))) unsigned int*)g,
                                   (__attribute__((address_space(3))) unsigned int*)l, 16, 0, 0);
}

// ---------------------------------------------------------------------------
// fp32 -> bf16 (convert ONCE; R4 proved per-tile fp32 re-reads cost ~18us):
// x->xb; [Wq;Wk;Wv;Wg;Wa;pad] -> Wc (1664x512); Wo->Wob.
// ---------------------------------------------------------------------------
__global__ __launch_bounds__(256) void conv_bf16(const float* __restrict__ x,
                                                 const float* __restrict__ Wq,
                                                 const float* __restrict__ Wk,
                                                 const float* __restrict__ Wv,
                                                 const float* __restrict__ Wo,
                                                 const float* __restrict__ Wg,
                                                 const float* __restrict__ Wa,
                                                 unsigned short* __restrict__ xb,
                                                 unsigned short* __restrict__ Wc,
                                                 unsigned short* __restrict__ Wob) {
  int idx = blockIdx.x * 256 + threadIdx.x;  // float4 index
  if (idx < 789504) {
    const float* src;
    unsigned short* dst;
    int off;
    if (idx < 524288)      { src = x;  dst = xb;           off = idx; }
    else if (idx < 589824) { src = Wq; dst = Wc;           off = idx - 524288; }
    else if (idx < 655360) { src = Wk; dst = Wc + 262144;  off = idx - 589824; }
    else if (idx < 720896) { src = Wv; dst = Wc + 524288;  off = idx - 655360; }
    else if (idx < 786432) { src = Wo; dst = Wob;          off = idx - 720896; }
    else if (idx < 788480) { src = Wg; dst = Wc + 786432;  off = idx - 786432; }
    else                   { src = Wa; dst = Wc + 794624;  off = idx - 788480; }
    float4 v = *(const float4*)&src[(size_t)off * 4];
    ushort4 o;
    o.x = f2bf(v.x); o.y = f2bf(v.y); o.z = f2bf(v.z); o.w = f2bf(v.w);
    *(ushort4*)&dst[(size_t)off * 4] = o;
  } else {
    int off = idx - 789504;  // zero pad rows 1560..1663
    ushort4 z = {0, 0, 0, 0};
    *(ushort4*)&Wc[798720 + (size_t)off * 4] = z;
  }
}

// ---------------------------------------------------------------------------
// QKV GEMM (round-2 proven): 512 threads, 128x128 tile, BK=32, 2-barrier loop
// with async global_load_lds (width 16) into linear LDS.
// ---------------------------------------------------------------------------
__global__ __launch_bounds__(512) void gemm_qkv(const unsigned short* __restrict__ A,
                                                const unsigned short* __restrict__ W,
                                                const float* __restrict__ bg,
                                                const float* __restrict__ ba,
                                                unsigned short* __restrict__ qkvb,
                                                float* __restrict__ gate,
                                                float* __restrict__ alpha) {
  __shared__ unsigned short As[4096];
  __shared__ unsigned short Bs[4096];
  const int tid = threadIdx.x;
  const int lane = tid & 63, wave = tid >> 6;
  const int m0 = blockIdx.y * 128, n0 = blockIdx.x * 128;
  const int mw = (wave >> 1) * 2, nw = (wave & 1) * 4;

  ffrag4 acc[2][4];
#pragma unroll
  for (int i = 0; i < 2; ++i)
#pragma unroll
    for (int j = 0; j < 4; ++j) acc[i][j] = (ffrag4){0.f, 0.f, 0.f, 0.f};

  const unsigned short* ag =
      A + (size_t)(m0 + (tid >> 6) * 16 + (tid & 15)) * Dn + ((tid >> 4) & 3) * 8;
  const unsigned short* wg =
      W + (size_t)(n0 + (tid >> 6) * 16 + (tid & 15)) * Dn + ((tid >> 4) & 3) * 8;
  unsigned short* asl = &As[wave * 512];  // wave-uniform LDS base (+lane*16B by HW)
  unsigned short* bsl = &Bs[wave * 512];

  for (int k0 = 0; k0 < Dn; k0 += 32) {
    __syncthreads();
    gload_lds16(ag + k0, asl);
    gload_lds16(wg + k0, bsl);
    __syncthreads();
    bfrag8 af[2], bf_[4];
#pragma unroll
    for (int mt = 0; mt < 2; ++mt)
      af[mt] = __builtin_bit_cast(bfrag8, *(const uint4*)&As[((mw + mt) * 64 + lane) * 8]);
#pragma unroll
    for (int nt = 0; nt < 4; ++nt)
      bf_[nt] = __builtin_bit_cast(bfrag8, *(const uint4*)&Bs[((nw + nt) * 64 + lane) * 8]);
#pragma unroll
    for (int mt = 0; mt < 2; ++mt)
#pragma unroll
      for (int nt = 0; nt < 4; ++nt)
        acc[mt][nt] = __builtin_amdgcn_mfma_f32_16x16x32_bf16(af[mt], bf_[nt], acc[mt][nt], 0, 0, 0);
  }

  const int quad = lane >> 4, l15 = lane & 15;
#pragma unroll
  for (int nt = 0; nt < 4; ++nt) {
    int col = n0 + (nw + nt) * 16 + l15;
#pragma unroll
    for (int mt = 0; mt < 2; ++mt) {
#pragma unroll
      for (int r = 0; r < 4; ++r) {
        int row = m0 + (mw + mt) * 16 + quad * 4 + r;
        float val = acc[mt][nt][r];
        if (col < 1536) {
          qkvb[(size_t)row * QS + col] = f2bf(val);
        } else if (col < 1552) {
          gate[(size_t)row * (Hn * KT) + (col - 1536)] = sigmoidf_(val + bg[col - 1536]);
        } else if (col < 1560) {
          alpha[(size_t)row * Hn + (col - 1552)] = sigmoidf_(val + ba[col - 1552]);
        }
      }
    }
  }
}

// ---------------------------------------------------------------------------
// Out-proj GEMM (round-2 proven): 256 threads, 64x64 tile, global_load_lds.
// ---------------------------------------------------------------------------
__global__ __launch_bounds__(256) void gemm_out(const unsigned short* __restrict__ A,
                                                const unsigned short* __restrict__ W,
                                                const float* __restrict__ bias,
                                                float* __restrict__ C) {
  __shared__ unsigned short As[2048];
  __shared__ unsigned short Bs[2048];
  const int tid = threadIdx.x;
  const int lane = tid & 63, wave = tid >> 6;
  const int m0 = blockIdx.y * 64, n0 = blockIdx.x * 64;
  const int mw = (wave >> 1) * 2, nw = (wave & 1) * 2;

  ffrag4 acc[2][2];
#pragma unroll
  for (int i = 0; i < 2; ++i)
#pragma unroll
    for (int j = 0; j < 2; ++j) acc[i][j] = (ffrag4){0.f, 0.f, 0.f, 0.f};

  const unsigned short* ag =
      A + (size_t)(m0 + (tid >> 6) * 16 + (tid & 15)) * Dn + ((tid >> 4) & 3) * 8;
  const unsigned short* wg =
      W + (size_t)(n0 + (tid >> 6) * 16 + (tid & 15)) * Dn + ((tid >> 4) & 3) * 8;
  unsigned short* asl = &As[wave * 512];
  unsigned short* bsl = &Bs[wave * 512];

  for (int k0 = 0; k0 < Dn; k0 += 32) {
    __syncthreads();
    gload_lds16(ag + k0, asl);
    gload_lds16(wg + k0, bsl);
    __syncthreads();
    bfrag8 af[2], bf_[2];
#pragma unroll
    for (int mt = 0; mt < 2; ++mt)
      af[mt] = __builtin_bit_cast(bfrag8, *(const uint4*)&As[((mw + mt) * 64 + lane) * 8]);
#pragma unroll
    for (int nt = 0; nt < 2; ++nt)
      bf_[nt] = __builtin_bit_cast(bfrag8, *(const uint4*)&Bs[((nw + nt) * 64 + lane) * 8]);
#pragma unroll
    for (int mt = 0; mt < 2; ++mt)
#pragma unroll
      for (int nt = 0; nt < 2; ++nt)
        acc[mt][nt] = __builtin_amdgcn_mfma_f32_16x16x32_bf16(af[mt], bf_[nt], acc[mt][nt], 0, 0, 0);
  }

  const int quad = lane >> 4, l15 = lane & 15;
#pragma unroll
  for (int nt = 0; nt < 2; ++nt) {
    int col = n0 + (nw + nt) * 16 + l15;
    float bb = bias[col];
#pragma unroll
    for (int mt = 0; mt < 2; ++mt) {
#pragma unroll
      for (int r = 0; r < 4; ++r) {
        int row = m0 + (mw + mt) * 16 + quad * 4 + r;
        C[(size_t)row * Dn + col] = acc[mt][nt][r] + bb;
      }
    }
  }
}

// ---------------------------------------------------------------------------
// Block per (b,h,c): S^T_k = (w_k o V)^T @ K via MFMA, z_k via wred, sval
// exported. LDS-transposes K,V; exports V^T tiles to vT. S^T now stored BF16
// (consumer Hinit is bf16 anyway) -- halves the chunk->scan round-trip.
// ---------------------------------------------------------------------------
__global__ __launch_bounds__(256) void chunk_sums(const unsigned short* __restrict__ qkvb,
                                                  const float* __restrict__ gate,
                                                  const float* __restrict__ decay,
                                                  unsigned short* __restrict__ S,
                                                  float* __restrict__ Zc,
                                                  float* __restrict__ svalb,
                                                  unsigned short* __restrict__ vT) {
  __shared__ unsigned short sK[64 * 72];
  __shared__ unsigned short sV[64 * 72];
  __shared__ unsigned short sKT[64 * 72];   // K^T: [i][t], stride 72
  __shared__ unsigned short sVT[64 * 72];   // V^T: [j][t], stride 72
  __shared__ float red4[256];
  __shared__ float sval_s[64];
  __shared__ float gk[KT][64];
  __shared__ float pwr[KT][64];
  __shared__ float wcomb[KT][64];
  const int c = blockIdx.x, h = blockIdx.y, b = blockIdx.z;
  const int c0 = c * 64;
  const int tid = threadIdx.x, wave = tid >> 6, lane = tid & 63;
  const int quad = lane >> 4, l15 = lane & 15;

  {
    int row = tid >> 2, cg = tid & 3;
    const us8v* ksrc = (const us8v*)&qkvb[(size_t)(b * Tn + c0 + row) * QS + 512 + h * DH + cg * 16];
    *(us8v*)&sK[row * 72 + cg * 16] = ksrc[0];
    *(us8v*)&sK[row * 72 + cg * 16 + 8] = ksrc[1];
    const us8v* vsrc = (const us8v*)&qkvb[(size_t)(b * Tn + c0 + row) * QS + 1024 + h * DH + cg * 16];
    *(us8v*)&sV[row * 72 + cg * 16] = vsrc[0];
    *(us8v*)&sV[row * 72 + cg * 16 + 8] = vsrc[1];
  }
  if (tid < 128) {
    int s = tid >> 1, k2 = tid & 1;
    gk[k2][s] = gate[((size_t)(b * Tn + c0 + s) * Hn + h) * KT + k2];
  } else {
    int t2 = tid - 128;
    int k2 = t2 >> 6, d = t2 & 63;
    pwr[k2][d] = powf(sigmoidf_(decay[h * KT + k2]), (float)d);
  }
  __syncthreads();
  {
    int row = tid >> 2, cg = tid & 3;
    float acc = 0.f;
#pragma unroll
    for (int u = 0; u < 16; ++u) acc += fabsf(bf2f(sK[row * 72 + cg * 16 + u]));
    red4[tid] = acc;
  }
  if (tid >= 128) {
    int t2 = tid - 128;
    int k2 = t2 >> 6, d = t2 & 63;
    wcomb[k2][d] = gk[k2][d] * pwr[k2][63 - d];
  }
  __syncthreads();
  if (tid < 64) {
    float sv = (red4[tid * 4] + red4[tid * 4 + 1] + red4[tid * 4 + 2] + red4[tid * 4 + 3]) *
                   (1.f / 64.f) + EPS;
    sval_s[tid] = sv;
    svalb[((size_t)(b * Hn + h)) * Tn + c0 + tid] = sv;
  }
  // LDS transpose of K and V; V^T also exported to vT (global).
  {
    int j = tid >> 2, tg = tid & 3;
    us8v a0, a1, b0, b1;
#pragma unroll
    for (int u = 0; u < 8; ++u) {
      a0[u] = sV[(tg * 16 + u) * 72 + j];
      a1[u] = sV[(tg * 16 + 8 + u) * 72 + j];
      b0[u] = sK[(tg * 16 + u) * 72 + j];
      b1[u] = sK[(tg * 16 + 8 + u) * 72 + j];
    }
    *(us8v*)&sVT[j * 72 + tg * 16] = a0;
    *(us8v*)&sVT[j * 72 + tg * 16 + 8] = a1;
    *(us8v*)&sKT[j * 72 + tg * 16] = b0;
    *(us8v*)&sKT[j * 72 + tg * 16 + 8] = b1;
    size_t vrow = ((size_t)((b * Hn + h) * 64 + j)) * Tn + c0 + tg * 16;
    *(us8v*)&vT[vrow] = a0;
    *(us8v*)&vT[vrow + 8] = a1;
  }
  __syncthreads();
  if (wave < 2) {
    const int kx = wave;
    float v = wcomb[kx][lane] * sval_s[lane];
    v = wred_sum(v);
    if (lane == 0) Zc[((size_t)((b * Hn + h) * KT + kx)) * NC + c] = v;
  }

  // S^T = (w o V)^T @ K : A-frag rows m=j (V dh), B-frag cols n=i (K dh).
  us8v kf2[4][2];
#pragma unroll
  for (int nt = 0; nt < 4; ++nt)
#pragma unroll
    for (int ks = 0; ks < 2; ++ks)
      kf2[nt][ks] = *(const us8v*)&sKT[(nt * 16 + l15) * 72 + ks * 32 + quad * 8];

  const int jrow = wave * 16 + l15;
  us8v vraw[2];
  vraw[0] = *(const us8v*)&sVT[jrow * 72 + quad * 8];
  vraw[1] = *(const us8v*)&sVT[jrow * 72 + 32 + quad * 8];

#pragma unroll
  for (int k = 0; k < KT; ++k) {
    us8v af[2];
#pragma unroll
    for (int ks = 0; ks < 2; ++ks) {
      float4 w0 = *(const float4*)&wcomb[k][ks * 32 + quad * 8];
      float4 w1 = *(const float4*)&wcomb[k][ks * 32 + quad * 8 + 4];
      af[ks][0] = f2bf(w0.x * bf2f(vraw[ks][0]));
      af[ks][1] = f2bf(w0.y * bf2f(vraw[ks][1]));
      af[ks][2] = f2bf(w0.z * bf2f(vraw[ks][2]));
      af[ks][3] = f2bf(w0.w * bf2f(vraw[ks][3]));
      af[ks][4] = f2bf(w1.x * bf2f(vraw[ks][4]));
      af[ks][5] = f2bf(w1.y * bf2f(vraw[ks][5]));
      af[ks][6] = f2bf(w1.z * bf2f(vraw[ks][6]));
      af[ks][7] = f2bf(w1.w * bf2f(vraw[ks][7]));
    }
    ffrag4 acc[4];
#pragma unroll
    for (int nt = 0; nt < 4; ++nt) acc[nt] = (ffrag4){0.f, 0.f, 0.f, 0.f};
#pragma unroll
    for (int nt = 0; nt < 4; ++nt)
#pragma unroll
      for (int ks = 0; ks < 2; ++ks)
        acc[nt] = __builtin_amdgcn_mfma_f32_16x16x32_bf16(
            __builtin_bit_cast(bfrag8, af[ks]), __builtin_bit_cast(bfrag8, kf2[nt][ks]), acc[nt], 0, 0, 0);
    const size_t sb = ((size_t)((b * Hn + h) * KT + k) * NC + c) * 4096;
#pragma unroll
    for (int nt = 0; nt < 4; ++nt)
#pragma unroll
      for (int r = 0; r < 4; ++r)
        S[sb + (size_t)(wave * 16 + quad * 4 + r) * 64 + nt * 16 + l15] = f2bf(acc[nt][r]);
  }
}

// ---------------------------------------------------------------------------
// Serial scan: bf16 S^T in, fp32 accumulator, bf16 Hinit^T out (elementwise,
// layout-agnostic). Batch-4 loads: 4 independent loads in flight per step.
// ---------------------------------------------------------------------------
__global__ __launch_bounds__(256) void scan_chunks(const unsigned short* __restrict__ S,
                                                   const float* __restrict__ Zc,
                                                   const float* __restrict__ decay,
                                                   unsigned short* __restrict__ Hinit,
                                                   float* __restrict__ Zinit) {
  const int bhk = blockIdx.x, slice = blockIdx.y;
  const int k = bhk % KT, h = (bhk / KT) % Hn;
  const float lam = sigmoidf_(decay[h * KT + k]);
  const float lam64 = powf(lam, 64.f);
  const int tid = threadIdx.x;
  const size_t base = (size_t)bhk * NC * 4096 + (size_t)slice * 512 + (size_t)tid * 2;
  float2 st = {0.f, 0.f};
  ushort2 sv[4];
#pragma unroll
  for (int j = 0; j < 4; ++j) sv[j] = *(const ushort2*)&S[base + (size_t)j * 4096];
  for (int cb = 0; cb < NC; cb += 4) {
    ushort2 nx[4] = {sv[0], sv[1], sv[2], sv[3]};
    if (cb + 4 < NC) {
#pragma unroll
      for (int j = 0; j < 4; ++j) nx[j] = *(const ushort2*)&S[base + (size_t)(cb + 4 + j) * 4096];
    }
#pragma unroll
    for (int j = 0; j < 4; ++j) {
      size_t off = base + (size_t)(cb + j) * 4096;
      ushort2 o;
      o.x = f2bf(st.x); o.y = f2bf(st.y);
      *(ushort2*)&Hinit[off] = o;
      st.x = lam64 * st.x + bf2f(sv[j].x);
      st.y = lam64 * st.y + bf2f(sv[j].y);
    }
#pragma unroll
    for (int j = 0; j < 4; ++j) sv[j] = nx[j];
  }
  if (slice == 0 && tid < 64) {
    float v = (tid < NC) ? Zc[bhk * NC + tid] : 0.f;
    float lp = lam64;
#pragma unroll
    for (int o = 1; o < 32; o <<= 1) {
      float t2 = __shfl_up(v, o, 64);
      if (tid >= o) v += lp * t2;
      lp *= lp;
    }
    float prev = __shfl_up(v, 1, 64);
    if (tid < NC) Zinit[bhk * NC + tid] = (tid == 0) ? 0.f : prev;
  }
}

// ---------------------------------------------------------------------------
// Block per (b,h,c): chunked attention. Hinit^T and V^T arrive pre-transposed,
// so every LDS->MFMA B-fragment is a contiguous ds_read_b128. Single staging
// barrier; prev-half V comes straight from sVTa (no restage). alpha cached in
// LDS (one coalesced 64-load instead of per-thread scattered scalars).
// ---------------------------------------------------------------------------
__global__ __launch_bounds__(256) void attn_chunk(const unsigned short* __restrict__ qkvb,
                                                  const float* __restrict__ gate,
                                                  const float* __restrict__ alpha,
                                                  const float* __restrict__ decay,
                                                  const unsigned short* __restrict__ Hinit,
                                                  const float* __restrict__ Zinit,
                                                  const float* __restrict__ svalb,
                                                  const unsigned short* __restrict__ vT,
                                                  unsigned short* __restrict__ ypre) {
  __shared__ float sS[64][132];               // raw scores -> probs (33.8 KB)
  __shared__ unsigned short sHT[KT][64 * 72]; // Hinit^T staging [j][i] (18.4 KB)
  __shared__ unsigned short sVTa[64 * 136];   // V^T staging [j][t prev|cur] (17.4 KB)
  __shared__ float sval_s[64];
  __shared__ float alp_s[64];
  __shared__ float gk[KT][64];
  __shared__ float sz[KT][64];
  __shared__ float pw[KT][66];
  __shared__ float wt2[KT][64];               // g_s * lam^-s
  __shared__ float zin[KT];

  const int c = blockIdx.x, h = blockIdx.y, b = blockIdx.z;
  const int c0 = c * 64;
  const int tid = threadIdx.x;
  const int wave = tid >> 6, lane = tid & 63;
  const int quad = lane >> 4, l15 = lane & 15;
  const int mt = wave;

  // ---------------- prologue ----------------
  if (tid < 64) {
    sval_s[tid] = svalb[((size_t)(b * Hn + h)) * Tn + c0 + tid];
    alp_s[tid] = alpha[((size_t)(b * Tn + c0 + tid)) * Hn + h];
  }
  if (tid >= 64 && tid < 192) {
    int t2 = tid - 64;
    int s = t2 >> 1, k2 = t2 & 1;
    gk[k2][s] = gate[((size_t)(b * Tn + c0 + s) * Hn + h) * KT + k2];
  }
  if (tid >= 128) {
    int t2 = tid - 128;
    int k2 = t2 >> 6, d = t2 & 63;
    float lamv = sigmoidf_(decay[h * KT + k2]);
    pw[k2][d] = powf(lamv, (float)d);
  }
  if (tid < 2) {
    float lamv = sigmoidf_(decay[h * KT + tid]);
    pw[tid][64] = powf(lamv, 64.f);
    zin[tid] = Zinit[((size_t)((b * Hn + h) * KT + tid)) * NC + c];
  }
  __syncthreads();
  if (tid >= 128) {
    int t2 = tid - 128;
    int k2 = t2 >> 6, d = t2 & 63;
    wt2[k2][d] = gk[k2][d] / pw[k2][d];   // lam^-d = 1/pw[d] (rcp, not powf)
  }
  if (wave < 2) {
    const int kx = wave;
    float v = gk[kx][lane] * sval_s[lane];
#pragma unroll
    for (int o = 1; o < 64; o <<= 1) {
      float t2 = __shfl_up(v, o, 64);
      if (lane >= o) v += pw[kx][o] * t2;
    }
    sz[kx][lane] = v + pw[kx][lane + 1] * zin[kx];
  }
  // wt2/sz consumed in C2, after the staging barrier below.

  // -------- issue staging loads early (regs): Hinit^T k0,k1 + V^T ----------
  us8v stgH[KT][2], stgV[4];
  {
    int j = tid >> 2, cg = tid & 3;
#pragma unroll
    for (int k = 0; k < KT; ++k) {
      const size_t hb = ((size_t)((b * Hn + h) * KT + k) * NC + c) * 4096;
      stgH[k][0] = *(const us8v*)&Hinit[hb + j * 64 + cg * 16];
      stgH[k][1] = *(const us8v*)&Hinit[hb + j * 64 + cg * 16 + 8];
    }
    const size_t vrow = ((size_t)((b * Hn + h) * 64 + j)) * Tn;
    const us8v z8 = (us8v){0, 0, 0, 0, 0, 0, 0, 0};
#pragma unroll
    for (int q = 0; q < 4; ++q) {
      int tt = c0 - 64 + cg * 32 + q * 8;
      stgV[q] = (tt >= 0) ? *(const us8v*)&vT[vrow + tt] : z8;
    }
  }

  // ---------------- Q fragments ----------------
  us8v qf[2];
  {
    const size_t qrow = (size_t)(b * Tn + c0 + mt * 16 + l15) * QS + h * DH;
    qf[0] = *(const us8v*)&qkvb[qrow + quad * 8];
    qf[1] = *(const us8v*)&qkvb[qrow + 32 + quad * 8];
  }

  // ---------------- phase A: raw scores = Qc @ Kwin^T ----------------------
#pragma unroll
  for (int nt = 0; nt < 8; ++nt) {
    int rowg = c0 - 64 + nt * 16 + l15;
    us8v kf0 = (us8v){0, 0, 0, 0, 0, 0, 0, 0}, kf1 = kf0;
    if (rowg >= 0) {
      const size_t kb_ = (size_t)(b * Tn + rowg) * QS + 512 + h * DH;
      kf0 = *(const us8v*)&qkvb[kb_ + quad * 8];
      kf1 = *(const us8v*)&qkvb[kb_ + 32 + quad * 8];
    }
    ffrag4 a = (ffrag4){0.f, 0.f, 0.f, 0.f};
    a = __builtin_amdgcn_mfma_f32_16x16x32_bf16(__builtin_bit_cast(bfrag8, qf[0]),
                                                __builtin_bit_cast(bfrag8, kf0), a, 0, 0, 0);
    a = __builtin_amdgcn_mfma_f32_16x16x32_bf16(__builtin_bit_cast(bfrag8, qf[1]),
                                                __builtin_bit_cast(bfrag8, kf1), a, 0, 0, 0);
#pragma unroll
    for (int r = 0; r < 4; ++r) sS[mt * 16 + quad * 4 + r][nt * 16 + l15] = a[r];
  }

  // -------- commit staging regs to LDS, single barrier ---------------------
  {
    int j = tid >> 2, cg = tid & 3;
#pragma unroll
    for (int k = 0; k < KT; ++k) {
      *(us8v*)&sHT[k][j * 72 + cg * 16] = stgH[k][0];
      *(us8v*)&sHT[k][j * 72 + cg * 16 + 8] = stgH[k][1];
    }
#pragma unroll
    for (int q = 0; q < 4; ++q)
      *(us8v*)&sVTa[j * 136 + cg * 32 + q * 8] = stgV[q];
  }
  __syncthreads();

  // ---------------- phase C1: accH_k = Q @ Hinit_k (contiguous b128) -------
  ffrag4 accH[KT][4];
#pragma unroll
  for (int k = 0; k < KT; ++k)
#pragma unroll
    for (int nt = 0; nt < 4; ++nt) accH[k][nt] = (ffrag4){0.f, 0.f, 0.f, 0.f};
#pragma unroll
  for (int k = 0; k < KT; ++k) {
#pragma unroll
    for (int nt = 0; nt < 4; ++nt) {
#pragma unroll
      for (int ks = 0; ks < 2; ++ks) {
        us8v g = *(const us8v*)&sHT[k][(nt * 16 + l15) * 72 + ks * 32 + quad * 8];
        accH[k][nt] = __builtin_amdgcn_mfma_f32_16x16x32_bf16(
            __builtin_bit_cast(bfrag8, qf[ks]), __builtin_bit_cast(bfrag8, g), accH[k][nt], 0, 0, 0);
      }
    }
  }

  // ---------------- cur-half V^T B-frags (contiguous b128) -----------------
  us8v vf[4][2];
#pragma unroll
  for (int nt = 0; nt < 4; ++nt)
#pragma unroll
    for (int ks = 0; ks < 2; ++ks)
      vf[nt][ks] = *(const us8v*)&sVTa[(nt * 16 + l15) * 136 + 64 + ks * 32 + quad * 8];

  // ---------------- phase C2 + combine into accY ---------------------------
  const int i_loc = mt * 16 + l15;
  ffrag4 accY[4];
#pragma unroll
  for (int nt = 0; nt < 4; ++nt) accY[nt] = (ffrag4){0.f, 0.f, 0.f, 0.f};
#pragma unroll
  for (int k = 0; k < KT; ++k) {
    const float lam_i = pw[k][i_loc];
    us8v af[2];
#pragma unroll
    for (int ks = 0; ks < 2; ++ks) {
      int sb_ = ks * 32 + quad * 8;
      float4 p0 = *(const float4*)&sS[i_loc][64 + sb_];
      float4 p1 = *(const float4*)&sS[i_loc][64 + sb_ + 4];
      float4 w0 = *(const float4*)&wt2[k][sb_];
      float4 w1 = *(const float4*)&wt2[k][sb_ + 4];
      float e[8] = {p0.x * w0.x, p0.y * w0.y, p0.z * w0.z, p0.w * w0.w,
                    p1.x * w1.x, p1.y * w1.y, p1.z * w1.z, p1.w * w1.w};
#pragma unroll
      for (int j = 0; j < 8; ++j) {
        float v = (sb_ + j <= i_loc) ? e[j] * lam_i : 0.f;
        af[ks][j] = f2bf(v);
      }
    }
    ffrag4 aD[4];
#pragma unroll
    for (int nt = 0; nt < 4; ++nt) aD[nt] = (ffrag4){0.f, 0.f, 0.f, 0.f};
#pragma unroll
    for (int nt = 0; nt < 4; ++nt)
#pragma unroll
      for (int ks = 0; ks < 2; ++ks)
        aD[nt] = __builtin_amdgcn_mfma_f32_16x16x32_bf16(
            __builtin_bit_cast(bfrag8, af[ks]), __builtin_bit_cast(bfrag8, vf[nt][ks]), aD[nt], 0, 0, 0);
#pragma unroll
    for (int nt = 0; nt < 4; ++nt) {
#pragma unroll
      for (int r = 0; r < 4; ++r) {
        int il = mt * 16 + quad * 4 + r;
        float invz = 1.f / (sz[k][il] + EPS);
        accY[nt][r] += (pw[k][il + 1] * accH[k][nt][r] + aD[nt][r]) * invz;
      }
    }
  }

  // ---------------- phase D: in-place masked ALiBi softmax -----------------
  {
    const float slope = exp2f(-8.f * (float)(h + 1) / (float)Hn);
    for (int rr = 0; rr < 16; ++rr) {
      const int i = mt * 16 + rr;
      float s0v = sS[i][lane], s1v = sS[i][lane + 64];
      bool va = (lane >= i + 1) && (c0 - 64 + lane >= 0);
      bool vb2 = (lane <= i);
      s0v = va  ? s0v - slope * (float)(i + 64 - lane) : -1e30f;
      s1v = vb2 ? s1v - slope * (float)(i - lane) : -1e30f;
      float m = wred_max(fmaxf(s0v, s1v));
      float p0 = __expf(s0v - m), p1 = __expf(s1v - m);
      float inv = 1.f / wred_sum(p0 + p1);
      sS[i][lane] = p0 * inv;
      sS[i][lane + 64] = p1 * inv;
    }
  }

  // ---------------- phase E: yloc = P @ Vwin (all frags from sVTa) ---------
  ffrag4 accL[4];
#pragma unroll
  for (int nt = 0; nt < 4; ++nt) accL[nt] = (ffrag4){0.f, 0.f, 0.f, 0.f};
  us8v pf[2];
#pragma unroll
  for (int ks = 0; ks < 2; ++ks) {
    int sb_ = ks * 32 + quad * 8;
    float4 p0 = *(const float4*)&sS[i_loc][64 + sb_];
    float4 p1 = *(const float4*)&sS[i_loc][64 + sb_ + 4];
    float e[8] = {p0.x, p0.y, p0.z, p0.w, p1.x, p1.y, p1.z, p1.w};
#pragma unroll
    for (int j = 0; j < 8; ++j) pf[ks][j] = f2bf(e[j]);
  }
#pragma unroll
  for (int nt = 0; nt < 4; ++nt)
#pragma unroll
    for (int ks = 0; ks < 2; ++ks)
      accL[nt] = __builtin_amdgcn_mfma_f32_16x16x32_bf16(
          __builtin_bit_cast(bfrag8, pf[ks]), __builtin_bit_cast(bfrag8, vf[nt][ks]), accL[nt], 0, 0, 0);

  // prev-half directly from sVTa (no restage, no barriers)
#pragma unroll
  for (int ks = 0; ks < 2; ++ks) {
    int sb_ = ks * 32 + quad * 8;
    float4 p0 = *(const float4*)&sS[i_loc][sb_];
    float4 p1 = *(const float4*)&sS[i_loc][sb_ + 4];
    float e[8] = {p0.x, p0.y, p0.z, p0.w, p1.x, p1.y, p1.z, p1.w};
#pragma unroll
    for (int j = 0; j < 8; ++j) pf[ks][j] = f2bf(e[j]);
  }
#pragma unroll
  for (int nt = 0; nt < 4; ++nt) {
#pragma unroll
    for (int ks = 0; ks < 2; ++ks) {
      us8v g = *(const us8v*)&sVTa[(nt * 16 + l15) * 136 + ks * 32 + quad * 8];
      accL[nt] = __builtin_amdgcn_mfma_f32_16x16x32_bf16(
          __builtin_bit_cast(bfrag8, pf[ks]), __builtin_bit_cast(bfrag8, g), accL[nt], 0, 0, 0);
    }
  }

  // ---------------- phase F: combine + bf16 write --------------------------
#pragma unroll
  for (int nt = 0; nt < 4; ++nt) {
#pragma unroll
    for (int r = 0; r < 4; ++r) {
      int il = mt * 16 + quad * 4 + r;
      int tt = c0 + il;
      float av = alp_s[il];
      float val = av * accL[nt][r] + (1.f - av) * accY[nt][r];
      ypre[(size_t)(b * Tn + tt) * Dn + h * DH + nt * 16 + l15] = f2bf(val);
    }
  }
}

// ---------------------------------------------------------------------------
// out = LayerNorm(x + proj) * gamma + beta
// ---------------------------------------------------------------------------
__global__ __launch_bounds__(256) void ln_kernel(const float* __restrict__ x,
                                                 const float* __restrict__ proj,
                                                 const float* __restrict__ gamma,
                                                 const float* __restrict__ beta,
                                                 float* __restrict__ out) {
  const int row = blockIdx.x;
  const int tid = threadIdx.x;
  const int wave = tid >> 6, lane = tid & 63;
  const size_t base = (size_t)row * Dn;
  __shared__ float red[8];
  float r0 = x[base + tid] + proj[base + tid];
  float r1 = x[base + tid + 256] + proj[base + tid + 256];
  float s = wred_sum(r0 + r1);
  if (lane == 0) red[wave] = s;
  __syncthreads();
  float mu = (red[0] + red[1] + red[2] + red[3]) * (1.f / (float)Dn);
  float d0 = r0 - mu, d1 = r1 - mu;
  float q = wred_sum(d0 * d0 + d1 * d1);
  if (lane == 0) red[4 + wave] = q;
  __syncthreads();
  float var = (red[4] + red[5] + red[6] + red[7]) * (1.f / (float)Dn);
  float inv = rsqrtf(var + LN_EPS);
  out[base + tid]       = d0 * inv * gamma[tid]       + beta[tid];
  out[base + tid + 256] = d1 * inv * gamma[tid + 256] + beta[tid + 256];
}

// ---------------------------------------------------------------------------
extern "C" void kernel_launch(void* const* d_in, const int* in_sizes, int n_in,
                              void* d_out, int out_size, void* d_ws, size_t ws_size,
                              hipStream_t stream) {
  const float* x     = (const float*)d_in[0];
  const float* Wq    = (const float*)d_in[1];
  const float* Wk    = (const float*)d_in[2];
  const float* Wv    = (const float*)d_in[3];
  const float* Wg    = (const float*)d_in[4];
  const float* bg    = (const float*)d_in[5];
  const float* Wa    = (const float*)d_in[6];
  const float* ba    = (const float*)d_in[7];
  const float* Wo    = (const float*)d_in[8];
  const float* bo    = (const float*)d_in[9];
  const float* decay = (const float*)d_in[10];
  const float* gamma = (const float*)d_in[11];
  const float* beta  = (const float*)d_in[12];
  float* out = (float*)d_out;

  const size_t NTOK = (size_t)Bn * Tn;                  // 4096
  const size_t NST  = (size_t)Bn * Hn * KT * NC * 4096; // 4194304 state elems
  float* ws = (float*)d_ws;
  float* proj  = ws; ws += NTOK * Dn;   // fp32 proj; bf16 vT overlays (time-disjoint)
  float* gateb = ws; ws += NTOK * Hn * KT;
  float* alphb = ws; ws += NTOK * Hn;
  float* Zcb   = ws; ws += (size_t)Bn * Hn * KT * NC;
  float* Zib   = ws; ws += (size_t)Bn * Hn * KT * NC;
  float* svalb = ws; ws += (size_t)Bn * Hn * Tn;
  unsigned short* us = (unsigned short*)ws;
  unsigned short* Sb   = us; us += NST;                  // bf16 S^T
  unsigned short* Hib  = us; us += NST;                  // bf16 Hinit^T
  unsigned short* xb   = us; us += NTOK * Dn;
  unsigned short* Wc   = us; us += (size_t)NW * Dn;      // 1664x512
  unsigned short* Wob  = us; us += (size_t)Dn * Dn;
  unsigned short* ypre = us; us += NTOK * Dn;
  unsigned short* qkvb = us; us += NTOK * QS;
  // vT (bf16 V^T, 4.2 MB) overlays proj (8.4 MB): vT is dead before gemm_out
  // writes proj (attn finished), so the regions are time-disjoint.
  unsigned short* vT = (unsigned short*)proj;

  conv_bf16<<<3136, 256, 0, stream>>>(x, Wq, Wk, Wv, Wo, Wg, Wa, xb, Wc, Wob);

  gemm_qkv<<<dim3(NW / 128, (int)NTOK / 128), 512, 0, stream>>>(
      xb, Wc, bg, ba, qkvb, gateb, alphb);

  chunk_sums<<<dim3(NC, Hn, Bn), 256, 0, stream>>>(qkvb, gateb, decay, Sb, Zcb, svalb, vT);
  scan_chunks<<<dim3(Bn * Hn * KT, 8), 256, 0, stream>>>(Sb, Zcb, decay, Hib, Zib);

  attn_chunk<<<dim3(NC, Hn, Bn), 256, 0, stream>>>(qkvb, gateb, alphb, decay,
                                                   Hib, Zib, svalb, vT, ypre);

  gemm_out<<<dim3(Dn / 64, (int)NTOK / 64), 256, 0, stream>>>(ypre, Wob, bo, proj);
  ln_kernel<<<(int)NTOK, 256, 0, stream>>>(x, proj, gamma, beta, out);
}